// Round 2
// baseline (369.993 us; speedup 1.0000x reference)
//
#include <hip/hip_runtime.h>
#include <cstdint>
#include <cstddef>

typedef __bf16 bf16;
typedef unsigned short u16;
typedef __bf16 bf16x8 __attribute__((ext_vector_type(8)));
typedef float f32x4 __attribute__((ext_vector_type(4)));

#define NB 2
#define NT 2048
#define NC 2048
#define NH 16
#define NKV 4
#define ND 128

// scale * log2(e) = (1/sqrt(128)) * 1.4426950408889634
#define SLOG2E 0.12751744061898285f

static __device__ __forceinline__ void gload16(const void* g, void* l) {
  __builtin_amdgcn_global_load_lds(
      (const __attribute__((address_space(1))) unsigned int*)g,
      (__attribute__((address_space(3))) unsigned int*)l, 16, 0, 0);
}

static __device__ __forceinline__ f32x4 mfma16(bf16x8 a, bf16x8 b, f32x4 c) {
  return __builtin_amdgcn_mfma_f32_16x16x32_bf16(a, b, c, 0, 0, 0);
}

// ---------------- cast x (f32 -> bf16), 8 elems/thread ----------------
// n = total elements; grid must be n / (256*8) exactly (n is a multiple).
__global__ void cast_x_k(const float* __restrict__ x, bf16* __restrict__ xb) {
  size_t i = ((size_t)blockIdx.x * 256 + threadIdx.x) * 8;
  float4 v0 = *(const float4*)(x + i);
  float4 v1 = *(const float4*)(x + i + 4);
  bf16x8 o;
  o[0] = (bf16)v0.x; o[1] = (bf16)v0.y; o[2] = (bf16)v0.z; o[3] = (bf16)v0.w;
  o[4] = (bf16)v1.x; o[5] = (bf16)v1.y; o[6] = (bf16)v1.z; o[7] = (bf16)v1.w;
  *(bf16x8*)(xb + i) = o;
}

// ------------- weight transpose+cast: dst[n][k] = src[k][n] -------------
// src is [2048][N] f32; dst rows (length 2048) already offset by caller.
__global__ void wtrans_k(const float* __restrict__ src, int N, bf16* __restrict__ dst) {
  __shared__ float tile[64][65];
  int k0 = blockIdx.x * 64, n0 = blockIdx.y * 64;
  int tid = threadIdx.x, c = tid & 63, r4 = tid >> 6;
#pragma unroll 4
  for (int i = 0; i < 16; i++) {
    int rr = i * 4 + r4;
    tile[c][rr] = src[(size_t)(k0 + rr) * N + n0 + c];
  }
  __syncthreads();
#pragma unroll 4
  for (int i = 0; i < 16; i++) {
    int nn = i * 4 + r4;
    dst[(size_t)(n0 + nn) * 2048 + k0 + c] = (bf16)tile[nn][c];
  }
}

// ---------------- GEMM: C[M][N] = A[M][K] * Bt[N][K]^T ----------------
// 128x128 tile, BK=64, 4 waves (2x2 of 64x64). LDS linear with XOR-swizzled
// global source (slot ^= row&7) so ds_read_b128 frags are ~2-way conflicts.
template <int F32OUT>
__global__ __launch_bounds__(256, 2) void gemm_bt(const bf16* __restrict__ A,
                                                  const bf16* __restrict__ Bt,
                                                  void* __restrict__ Cp,
                                                  int M, int N, int K) {
  __shared__ __align__(16) char aT[16384];
  __shared__ __align__(16) char bT[16384];
  const int m0 = blockIdx.x * 128, n0 = blockIdx.y * 128;
  const int tid = threadIdx.x, w = tid >> 6, l = tid & 63;
  const int lr = l & 15, lg = l >> 4;
  const int wm = (w >> 1) * 64, wn = (w & 1) * 64;
  f32x4 acc[4][4] = {};
  for (int k0 = 0; k0 < K; k0 += 64) {
#pragma unroll
    for (int i = 0; i < 4; i++) {
      int p = i * 256 + tid;
      int row = p >> 3, sl = (p & 7) ^ (row & 7);
      gload16(A + (size_t)(m0 + row) * K + (k0 + sl * 8), aT + (i * 256 + w * 64) * 16);
      gload16(Bt + (size_t)(n0 + row) * K + (k0 + sl * 8), bT + (i * 256 + w * 64) * 16);
    }
    __syncthreads();
#pragma unroll
    for (int kc = 0; kc < 2; kc++) {
      bf16x8 af[4], bfr[4];
#pragma unroll
      for (int mi = 0; mi < 4; mi++) {
        int row = wm + mi * 16 + lr;
        af[mi] = *(const bf16x8*)(aT + row * 128 + (((kc * 4 + lg) ^ (row & 7)) * 16));
      }
#pragma unroll
      for (int ni = 0; ni < 4; ni++) {
        int row = wn + ni * 16 + lr;
        bfr[ni] = *(const bf16x8*)(bT + row * 128 + (((kc * 4 + lg) ^ (row & 7)) * 16));
      }
#pragma unroll
      for (int mi = 0; mi < 4; mi++)
#pragma unroll
        for (int ni = 0; ni < 4; ni++)
          acc[mi][ni] = mfma16(af[mi], bfr[ni], acc[mi][ni]);
    }
    __syncthreads();
  }
#pragma unroll
  for (int mi = 0; mi < 4; mi++)
#pragma unroll
    for (int ni = 0; ni < 4; ni++)
#pragma unroll
      for (int j = 0; j < 4; j++) {
        size_t row = (size_t)m0 + wm + mi * 16 + lg * 4 + j;
        size_t col = (size_t)n0 + wn + ni * 16 + lr;
        if (F32OUT)
          ((float*)Cp)[row * N + col] = acc[mi][ni][j];
        else
          ((bf16*)Cp)[row * N + col] = (bf16)acc[mi][ni][j];
      }
}

// ---------------- RoPE on q and k (f32 math), relayout ----------------
// qkv[b*T+t][3072]: q cols h*128+d, k cols 2048+kv*128+d, v cols 2560+...
__global__ void rope_k(const bf16* __restrict__ qkv, const float* __restrict__ cosg,
                       const float* __restrict__ sing, bf16* __restrict__ q_r,
                       bf16* __restrict__ k_r) {
  int blk = blockIdx.x;
  int b = blk >> 11, t = blk & 2047;
  const bf16* row = qkv + (size_t)blk * 3072;
  int tid = threadIdx.x;
#pragma unroll
  for (int i = 0; i < 4; i++) {
    int idx = i * 256 + tid;
    int hh = idx >> 6, dp = idx & 63;
    float a = (float)row[hh * 128 + dp], b2 = (float)row[hh * 128 + dp + 64];
    float c = cosg[t * 128 + dp], sn = sing[t * 128 + dp];
    bf16* dst = q_r + ((size_t)(b * NH + hh) * NT + t) * ND + dp;
    dst[0] = (bf16)(a * c - b2 * sn);
    dst[64] = (bf16)(b2 * c + a * sn);
  }
  {
    int kvh = tid >> 6, dp = tid & 63;
    float a = (float)row[2048 + kvh * 128 + dp], b2 = (float)row[2048 + kvh * 128 + dp + 64];
    float c = cosg[t * 128 + dp], sn = sing[t * 128 + dp];
    bf16* dst = k_r + ((size_t)(b * NKV + kvh) * NT + t) * ND + dp;
    dst[0] = (bf16)(a * c - b2 * sn);
    dst[64] = (bf16)(b2 * c + a * sn);
  }
}

// --------- v transpose: qkv v-cols -> vT[b][kv][d][t] (LDS tiled) ---------
__global__ void vtrans_k(const bf16* __restrict__ qkv, bf16* __restrict__ vT) {
  __shared__ u16 tile[64][66];
  int y = blockIdx.y;
  int b = y >> 3, kvh = (y >> 1) & 3, dh = y & 1;
  int t0 = blockIdx.x * 64;
  int tid = threadIdx.x, c = tid & 63, r4 = tid >> 6;
#pragma unroll 4
  for (int i = 0; i < 16; i++) {
    int rr = i * 4 + r4;  // t index
    tile[c][rr] = *(const u16*)(qkv + (size_t)(b * NT + t0 + rr) * 3072 + 2560 + kvh * 128 + dh * 64 + c);
  }
  __syncthreads();
#pragma unroll 4
  for (int i = 0; i < 16; i++) {
    int dd = i * 4 + r4;
    *(u16*)(vT + ((size_t)(b * NKV + kvh) * ND + dh * 64 + dd) * NT + t0 + c) = tile[dd][c];
  }
}

// ---------------- flash attention (causal, GQA 4:1) ----------------
// grid (T/128, B*H); 4 waves x 32 q-rows; KV tiles of 64.
__global__ __launch_bounds__(256, 2) void attn_k(const bf16* __restrict__ q_r,
                                                 const bf16* __restrict__ k_r,
                                                 const bf16* __restrict__ vT,
                                                 bf16* __restrict__ o) {
  __shared__ __align__(16) char kbuf[16384];  // [64 key][128 d], 16 slots/row, swz
  __shared__ __align__(16) char vbuf[16384];  // [128 d][64 key], 8 slots/row, swz
  __shared__ __align__(16) char pbuf[16384];  // per-wave [32 q][64 key], swz
  const int bx = blockIdx.x, bh = blockIdx.y;
  const int b = bh >> 4, h = bh & 15, kvh = h >> 2;
  const int tid = threadIdx.x, w = tid >> 6, l = tid & 63;
  const int lr = l & 15, lg = l >> 4;
  const int q0 = bx * 128 + w * 32;

  const bf16* qg = q_r + ((size_t)(b * NH + h) * NT + q0) * ND;
  bf16x8 qf[2][4];
#pragma unroll
  for (int mi = 0; mi < 2; mi++)
#pragma unroll
    for (int kc = 0; kc < 4; kc++)
      qf[mi][kc] = *(const bf16x8*)(qg + (size_t)(mi * 16 + lr) * ND + kc * 32 + lg * 8);

  f32x4 acc_o[2][8] = {};
  float mrun[2][4], lrun[2][4];
#pragma unroll
  for (int mi = 0; mi < 2; mi++)
#pragma unroll
    for (int jj = 0; jj < 4; jj++) { mrun[mi][jj] = -1e30f; lrun[mi][jj] = 0.f; }

  const bf16* kg = k_r + (size_t)(b * NKV + kvh) * NT * ND;
  const bf16* vg = vT + (size_t)(b * NKV + kvh) * ND * NT;
  const int ntiles = bx * 2 + 2;

  for (int tt = 0; tt < ntiles; ++tt) {
    const int kv0 = tt * 64;
#pragma unroll
    for (int i = 0; i < 4; i++) {  // K tile: 64 rows x 256B
      int p = i * 256 + tid;
      int row = p >> 4, sl = (p & 15) ^ (row & 7);
      gload16(kg + (size_t)(kv0 + row) * ND + sl * 8, kbuf + (i * 256 + w * 64) * 16);
    }
#pragma unroll
    for (int i = 0; i < 4; i++) {  // V^T tile: 128 rows x 128B
      int p = i * 256 + tid;
      int row = p >> 3, sl = (p & 7) ^ (row & 7);
      gload16(vg + (size_t)row * NT + kv0 + sl * 8, vbuf + (i * 256 + w * 64) * 16);
    }
    __syncthreads();

    // S = Q K^T
    f32x4 sacc[2][4] = {};
#pragma unroll
    for (int kc = 0; kc < 4; kc++) {
      bf16x8 kf[4];
#pragma unroll
      for (int ni = 0; ni < 4; ni++) {
        int key = ni * 16 + lr;
        kf[ni] = *(const bf16x8*)(kbuf + key * 256 + (((kc * 4 + lg) ^ (key & 7)) * 16));
      }
#pragma unroll
      for (int mi = 0; mi < 2; mi++)
#pragma unroll
        for (int ni = 0; ni < 4; ni++)
          sacc[mi][ni] = mfma16(qf[mi][kc], kf[ni], sacc[mi][ni]);
    }

    // online softmax (exp2 domain), row stats across 16 lanes via shfl_xor
    float pw[2][4][4];
    f32x4 rv[2];
#pragma unroll
    for (int mi = 0; mi < 2; mi++) {
#pragma unroll
      for (int jj = 0; jj < 4; jj++) {
        int qrow = q0 + mi * 16 + lg * 4 + jj;
        float sv[4];
        float mt = -1e30f;
#pragma unroll
        for (int ni = 0; ni < 4; ni++) {
          int key = kv0 + ni * 16 + lr;
          float xv = sacc[mi][ni][jj] * SLOG2E;
          xv = (key <= qrow) ? xv : -1e30f;
          sv[ni] = xv;
          mt = fmaxf(mt, xv);
        }
        mt = fmaxf(mt, __shfl_xor(mt, 1));
        mt = fmaxf(mt, __shfl_xor(mt, 2));
        mt = fmaxf(mt, __shfl_xor(mt, 4));
        mt = fmaxf(mt, __shfl_xor(mt, 8));
        float mold = mrun[mi][jj];
        float mnew = fmaxf(mold, mt);
        float r = exp2f(mold - mnew);
        mrun[mi][jj] = mnew;
        float rs = 0.f;
#pragma unroll
        for (int ni = 0; ni < 4; ni++) {
          float pp = exp2f(sv[ni] - mnew);
          pw[mi][ni][jj] = pp;
          rs += pp;
        }
        rs += __shfl_xor(rs, 1);
        rs += __shfl_xor(rs, 2);
        rs += __shfl_xor(rs, 4);
        rs += __shfl_xor(rs, 8);
        lrun[mi][jj] = lrun[mi][jj] * r + rs;
        rv[mi][jj] = r;
      }
    }
#pragma unroll
    for (int mi = 0; mi < 2; mi++)
#pragma unroll
      for (int dti = 0; dti < 8; dti++)
        acc_o[mi][dti] *= rv[mi];

    // P -> LDS (bf16, swizzled), per-wave region
#pragma unroll
    for (int mi = 0; mi < 2; mi++)
#pragma unroll
      for (int ni = 0; ni < 4; ni++)
#pragma unroll
        for (int jj = 0; jj < 4; jj++) {
          int qr = mi * 16 + lg * 4 + jj;
          int key = ni * 16 + lr;
          *(bf16*)(pbuf + w * 4096 + qr * 128 + ((key * 2) ^ ((qr & 7) << 4))) =
              (bf16)pw[mi][ni][jj];
        }

    // O += P V
#pragma unroll
    for (int kc = 0; kc < 2; kc++) {
      bf16x8 pf[2];
#pragma unroll
      for (int mi = 0; mi < 2; mi++) {
        int qr = mi * 16 + lr;
        pf[mi] = *(const bf16x8*)(pbuf + w * 4096 + qr * 128 + (((kc * 4 + lg) ^ (qr & 7)) * 16));
      }
#pragma unroll
      for (int dti = 0; dti < 8; dti++) {
        int d = dti * 16 + lr;
        bf16x8 vf = *(const bf16x8*)(vbuf + d * 128 + (((kc * 4 + lg) ^ (d & 7)) * 16));
#pragma unroll
        for (int mi = 0; mi < 2; mi++)
          acc_o[mi][dti] = mfma16(pf[mi], vf, acc_o[mi][dti]);
      }
    }
    __syncthreads();
  }

  // epilogue: O / l -> bf16 [b*T+t][h*128+d]
#pragma unroll
  for (int mi = 0; mi < 2; mi++) {
    f32x4 inv;
#pragma unroll
    for (int jj = 0; jj < 4; jj++) inv[jj] = 1.0f / lrun[mi][jj];
#pragma unroll
    for (int dti = 0; dti < 8; dti++) {
      f32x4 ov = acc_o[mi][dti] * inv;
#pragma unroll
      for (int jj = 0; jj < 4; jj++) {
        size_t orow = (size_t)b * NT + q0 + mi * 16 + lg * 4 + jj;
        o[orow * NC + h * ND + dti * 16 + lr] = (bf16)ov[jj];
      }
    }
  }
}

extern "C" void kernel_launch(void* const* d_in, const int* in_sizes, int n_in,
                              void* d_out, int out_size, void* d_ws, size_t ws_size,
                              hipStream_t stream) {
  const float* x = (const float*)d_in[0];
  const float* rc = (const float*)d_in[1];
  const float* rs = (const float*)d_in[2];
  const float* wq = (const float*)d_in[3];
  const float* wk = (const float*)d_in[4];
  const float* wv = (const float*)d_in[5];
  const float* wo = (const float*)d_in[6];

  // Workspace layout with reuse (68 MB total):
  //   [0,        25165824)  qkv [4096][3072] bf16; after rope+vtrans dead ->
  //                         reused as ob [4096][2048] bf16 (16.78 MB)
  //   [25165824, 41943040)  xb [4096][2048] bf16; dead after gemm1 ->
  //                         reused as q_r [2][16][2048][128] bf16 (same size)
  //   [41943040, 54525952)  wqkvT [3072][2048] bf16
  //   [54525952, 62914560)  woT [2048][2048] bf16
  //   [62914560, 67108864)  k_r [2][4][2048][128] bf16
  //   [67108864, 71303168)  vT  [2][4][128][2048] bf16
  char* ws = (char*)d_ws;
  bf16* qkv = (bf16*)(ws + 0);
  bf16* ob = (bf16*)(ws + 0);
  bf16* xb = (bf16*)(ws + 25165824);
  bf16* q_r = (bf16*)(ws + 25165824);
  bf16* wqkvT = (bf16*)(ws + 41943040);
  bf16* woT = (bf16*)(ws + 54525952);
  bf16* k_r = (bf16*)(ws + 62914560);
  bf16* vTb = (bf16*)(ws + 67108864);
  float* out = (float*)d_out;

  // x: B*T*C = 8388608 elements -> 8 per thread, 256 thr/blk -> 4096 blocks
  cast_x_k<<<4096, 256, 0, stream>>>(x, xb);
  wtrans_k<<<dim3(32, 32), 256, 0, stream>>>(wq, 2048, wqkvT);
  wtrans_k<<<dim3(32, 8), 256, 0, stream>>>(wk, 512, wqkvT + (size_t)2048 * 2048);
  wtrans_k<<<dim3(32, 8), 256, 0, stream>>>(wv, 512, wqkvT + (size_t)2560 * 2048);
  wtrans_k<<<dim3(32, 32), 256, 0, stream>>>(wo, 2048, woT);
  gemm_bt<0><<<dim3(32, 24), 256, 0, stream>>>(xb, wqkvT, qkv, 4096, 3072, 2048);
  rope_k<<<4096, 256, 0, stream>>>(qkv, rc, rs, q_r, k_r);
  vtrans_k<<<dim3(32, 16), 256, 0, stream>>>(qkv, vTb);
  attn_k<<<dim3(16, 32), 256, 0, stream>>>(q_r, k_r, vTb, ob);
  gemm_bt<1><<<dim3(32, 16), 256, 0, stream>>>(ob, woT, out, 4096, 2048, 2048);
}

// Round 3
// 325.299 us; speedup vs baseline: 1.1374x; 1.1374x over previous
//
#include <hip/hip_runtime.h>
#include <cstdint>
#include <cstddef>

typedef __bf16 bf16;
typedef unsigned short u16;
typedef __bf16 bf16x8 __attribute__((ext_vector_type(8)));
typedef float f32x4 __attribute__((ext_vector_type(4)));

#define NB 2
#define NT 2048
#define NC 2048
#define NH 16
#define NKV 4
#define ND 128

// scale * log2(e) = (1/sqrt(128)) * 1.4426950408889634
#define SLOG2E 0.12751744061898285f

static __device__ __forceinline__ void gload16(const void* g, void* l) {
  __builtin_amdgcn_global_load_lds(
      (const __attribute__((address_space(1))) unsigned int*)g,
      (__attribute__((address_space(3))) unsigned int*)l, 16, 0, 0);
}

static __device__ __forceinline__ f32x4 mfma16(bf16x8 a, bf16x8 b, f32x4 c) {
  return __builtin_amdgcn_mfma_f32_16x16x32_bf16(a, b, c, 0, 0, 0);
}

// ---------------- cast x (f32 -> bf16), 8 elems/thread ----------------
__global__ void cast_x_k(const float* __restrict__ x, bf16* __restrict__ xb) {
  size_t i = ((size_t)blockIdx.x * 256 + threadIdx.x) * 8;
  float4 v0 = *(const float4*)(x + i);
  float4 v1 = *(const float4*)(x + i + 4);
  bf16x8 o;
  o[0] = (bf16)v0.x; o[1] = (bf16)v0.y; o[2] = (bf16)v0.z; o[3] = (bf16)v0.w;
  o[4] = (bf16)v1.x; o[5] = (bf16)v1.y; o[6] = (bf16)v1.z; o[7] = (bf16)v1.w;
  *(bf16x8*)(xb + i) = o;
}

// ------------- weight transpose+cast: dst[n][k] = src[k][n] -------------
__global__ void wtrans_k(const float* __restrict__ src, int N, bf16* __restrict__ dst) {
  __shared__ float tile[64][65];
  int k0 = blockIdx.x * 64, n0 = blockIdx.y * 64;
  int tid = threadIdx.x, c = tid & 63, r4 = tid >> 6;
#pragma unroll 4
  for (int i = 0; i < 16; i++) {
    int rr = i * 4 + r4;
    tile[c][rr] = src[(size_t)(k0 + rr) * N + n0 + c];
  }
  __syncthreads();
#pragma unroll 4
  for (int i = 0; i < 16; i++) {
    int nn = i * 4 + r4;
    dst[(size_t)(n0 + nn) * 2048 + k0 + c] = (bf16)tile[nn][c];
  }
}

// ---------------- GEMM: C[M][N] = A[M][K] * Bt[N][K]^T ----------------
template <int F32OUT>
__global__ __launch_bounds__(256, 2) void gemm_bt(const bf16* __restrict__ A,
                                                  const bf16* __restrict__ Bt,
                                                  void* __restrict__ Cp,
                                                  int M, int N, int K) {
  __shared__ __align__(16) char aT[16384];
  __shared__ __align__(16) char bT[16384];
  const int m0 = blockIdx.x * 128, n0 = blockIdx.y * 128;
  const int tid = threadIdx.x, w = tid >> 6, l = tid & 63;
  const int lr = l & 15, lg = l >> 4;
  const int wm = (w >> 1) * 64, wn = (w & 1) * 64;
  f32x4 acc[4][4] = {};
  for (int k0 = 0; k0 < K; k0 += 64) {
#pragma unroll
    for (int i = 0; i < 4; i++) {
      int p = i * 256 + tid;
      int row = p >> 3, sl = (p & 7) ^ (row & 7);
      gload16(A + (size_t)(m0 + row) * K + (k0 + sl * 8), aT + (i * 256 + w * 64) * 16);
      gload16(Bt + (size_t)(n0 + row) * K + (k0 + sl * 8), bT + (i * 256 + w * 64) * 16);
    }
    __syncthreads();
#pragma unroll
    for (int kc = 0; kc < 2; kc++) {
      bf16x8 af[4], bfr[4];
#pragma unroll
      for (int mi = 0; mi < 4; mi++) {
        int row = wm + mi * 16 + lr;
        af[mi] = *(const bf16x8*)(aT + row * 128 + (((kc * 4 + lg) ^ (row & 7)) * 16));
      }
#pragma unroll
      for (int ni = 0; ni < 4; ni++) {
        int row = wn + ni * 16 + lr;
        bfr[ni] = *(const bf16x8*)(bT + row * 128 + (((kc * 4 + lg) ^ (row & 7)) * 16));
      }
#pragma unroll
      for (int mi = 0; mi < 4; mi++)
#pragma unroll
        for (int ni = 0; ni < 4; ni++)
          acc[mi][ni] = mfma16(af[mi], bfr[ni], acc[mi][ni]);
    }
    __syncthreads();
  }
#pragma unroll
  for (int mi = 0; mi < 4; mi++)
#pragma unroll
    for (int ni = 0; ni < 4; ni++)
#pragma unroll
      for (int j = 0; j < 4; j++) {
        size_t row = (size_t)m0 + wm + mi * 16 + lg * 4 + j;
        size_t col = (size_t)n0 + wn + ni * 16 + lr;
        if (F32OUT)
          ((float*)Cp)[row * N + col] = acc[mi][ni][j];
        else
          ((bf16*)Cp)[row * N + col] = (bf16)acc[mi][ni][j];
      }
}

// ---------------- RoPE on q and k (f32 math), relayout ----------------
__global__ void rope_k(const bf16* __restrict__ qkv, const float* __restrict__ cosg,
                       const float* __restrict__ sing, bf16* __restrict__ q_r,
                       bf16* __restrict__ k_r) {
  int blk = blockIdx.x;
  int b = blk >> 11, t = blk & 2047;
  const bf16* row = qkv + (size_t)blk * 3072;
  int tid = threadIdx.x;
#pragma unroll
  for (int i = 0; i < 4; i++) {
    int idx = i * 256 + tid;
    int hh = idx >> 6, dp = idx & 63;
    float a = (float)row[hh * 128 + dp], b2 = (float)row[hh * 128 + dp + 64];
    float c = cosg[t * 128 + dp], sn = sing[t * 128 + dp];
    bf16* dst = q_r + ((size_t)(b * NH + hh) * NT + t) * ND + dp;
    dst[0] = (bf16)(a * c - b2 * sn);
    dst[64] = (bf16)(b2 * c + a * sn);
  }
  {
    int kvh = tid >> 6, dp = tid & 63;
    float a = (float)row[2048 + kvh * 128 + dp], b2 = (float)row[2048 + kvh * 128 + dp + 64];
    float c = cosg[t * 128 + dp], sn = sing[t * 128 + dp];
    bf16* dst = k_r + ((size_t)(b * NKV + kvh) * NT + t) * ND + dp;
    dst[0] = (bf16)(a * c - b2 * sn);
    dst[64] = (bf16)(b2 * c + a * sn);
  }
}

// --------- v transpose: qkv v-cols -> vT[b][kv][d][t] (LDS tiled) ---------
__global__ void vtrans_k(const bf16* __restrict__ qkv, bf16* __restrict__ vT) {
  __shared__ u16 tile[64][66];
  int y = blockIdx.y;
  int b = y >> 3, kvh = (y >> 1) & 3, dh = y & 1;
  int t0 = blockIdx.x * 64;
  int tid = threadIdx.x, c = tid & 63, r4 = tid >> 6;
#pragma unroll 4
  for (int i = 0; i < 16; i++) {
    int rr = i * 4 + r4;  // t index
    tile[c][rr] = *(const u16*)(qkv + (size_t)(b * NT + t0 + rr) * 3072 + 2560 + kvh * 128 + dh * 64 + c);
  }
  __syncthreads();
#pragma unroll 4
  for (int i = 0; i < 16; i++) {
    int dd = i * 4 + r4;
    *(u16*)(vT + ((size_t)(b * NKV + kvh) * ND + dh * 64 + dd) * NT + t0 + c) = tile[dd][c];
  }
}

// ---------------- flash attention (causal, GQA 4:1) ----------------
// grid (16, B*H). Block handles the BALANCED PAIR of 64-row q-tiles
// (p, 31-p): (p+1) + (32-p) = 33 KV tiles of 64 keys -> uniform work.
// K/V double-buffered in LDS; next tile's global_load_lds issued before
// computing the current tile (2-phase prefetch), one barrier per tile.
__global__ __launch_bounds__(256, 2) void attn_k(const bf16* __restrict__ q_r,
                                                 const bf16* __restrict__ k_r,
                                                 const bf16* __restrict__ vT,
                                                 bf16* __restrict__ o) {
  __shared__ __align__(16) char kb[2][16384];  // [64 key][128 d] swz
  __shared__ __align__(16) char vb[2][16384];  // [128 d][64 key] swz
  __shared__ __align__(16) char pb[8192];      // per-wave [16 q][64 key] swz
  const int p = blockIdx.x, bh = blockIdx.y;
  const int b = bh >> 4, h = bh & 15, kvh = h >> 2;
  const int tid = threadIdx.x, w = tid >> 6, l = tid & 63;
  const int lr = l & 15, lg = l >> 4;
  const int nta = p + 1;       // KV tiles for q-tile A
  const int ntot = 33;         // + (32 - p) for q-tile B
  const int qA = p * 64, qB = (31 - p) * 64;

  const bf16* kg = k_r + (size_t)(b * NKV + kvh) * NT * ND;
  const bf16* vg = vT + (size_t)(b * NKV + kvh) * ND * NT;
  const bf16* qbase = q_r + (size_t)(b * NH + h) * NT * ND;

  bf16x8 qf[4];
  f32x4 acc_o[8];
  float mrun[4], lrun[4];

  auto loadq = [&](int qrow0) {
#pragma unroll
    for (int kc = 0; kc < 4; kc++)
      qf[kc] = *(const bf16x8*)(qbase + (size_t)(qrow0 + w * 16 + lr) * ND + kc * 32 + lg * 8);
  };
  auto reset_state = [&]() {
#pragma unroll
    for (int dti = 0; dti < 8; dti++) acc_o[dti] = f32x4{0.f, 0.f, 0.f, 0.f};
#pragma unroll
    for (int jj = 0; jj < 4; jj++) { mrun[jj] = -1e30f; lrun[jj] = 0.f; }
  };
  auto epilogue = [&](int qrow0) {
    f32x4 inv;
#pragma unroll
    for (int jj = 0; jj < 4; jj++) inv[jj] = 1.0f / lrun[jj];
#pragma unroll
    for (int dti = 0; dti < 8; dti++) {
      f32x4 ov = acc_o[dti] * inv;
#pragma unroll
      for (int jj = 0; jj < 4; jj++) {
        size_t orow = (size_t)b * NT + qrow0 + w * 16 + lg * 4 + jj;
        o[orow * NC + h * ND + dti * 16 + lr] = (bf16)ov[jj];
      }
    }
  };
  auto stage = [&](char* kd, char* vd, int kv0s) {
#pragma unroll
    for (int i = 0; i < 4; i++) {
      int pp = i * 256 + tid;
      int krow = pp >> 4, ksl = (pp & 15) ^ (krow & 7);
      gload16(kg + (size_t)(kv0s + krow) * ND + ksl * 8, kd + (i * 256 + w * 64) * 16);
      int vrow = pp >> 3, vsl = (pp & 7) ^ (vrow & 7);
      gload16(vg + (size_t)vrow * NT + kv0s + vsl * 8, vd + (i * 256 + w * 64) * 16);
    }
  };

  loadq(qA);
  reset_state();
  int q0 = qA;

  stage(kb[0], vb[0], 0);
  __syncthreads();

  for (int tt = 0; tt < ntot; ++tt) {
    const int cur = tt & 1;
    char* kcur = kb[cur];
    char* vcur = vb[cur];
    // prefetch next tile into the other buffer (lands by end-of-iter sync)
    if (tt + 1 < ntot) {
      int nx = tt + 1;
      int kv0n = (nx < nta ? nx : nx - nta) * 64;
      stage(kb[cur ^ 1], vb[cur ^ 1], kv0n);
    }
    // q-tile switch A -> B
    if (tt == nta) {
      epilogue(qA);
      loadq(qB);
      reset_state();
      q0 = qB;
    }
    const int kv0 = (tt < nta ? tt : tt - nta) * 64;

    // S = Q K^T
    f32x4 sacc[4] = {};
    __builtin_amdgcn_s_setprio(1);
#pragma unroll
    for (int kc = 0; kc < 4; kc++) {
#pragma unroll
      for (int ni = 0; ni < 4; ni++) {
        int key = ni * 16 + lr;
        bf16x8 kf = *(const bf16x8*)(kcur + key * 256 + (((kc * 4 + lg) ^ (key & 7)) * 16));
        sacc[ni] = mfma16(qf[kc], kf, sacc[ni]);
      }
    }
    __builtin_amdgcn_s_setprio(0);

    // online softmax (exp2 domain), 16-lane row reduce
    float pw[4][4];
    f32x4 rv;
#pragma unroll
    for (int jj = 0; jj < 4; jj++) {
      int qrow = q0 + w * 16 + lg * 4 + jj;
      float sv[4];
      float mt = -1e30f;
#pragma unroll
      for (int ni = 0; ni < 4; ni++) {
        int key = kv0 + ni * 16 + lr;
        float xv = sacc[ni][jj] * SLOG2E;
        xv = (key <= qrow) ? xv : -1e30f;
        sv[ni] = xv;
        mt = fmaxf(mt, xv);
      }
      mt = fmaxf(mt, __shfl_xor(mt, 1));
      mt = fmaxf(mt, __shfl_xor(mt, 2));
      mt = fmaxf(mt, __shfl_xor(mt, 4));
      mt = fmaxf(mt, __shfl_xor(mt, 8));
      float mold = mrun[jj];
      float mnew = fmaxf(mold, mt);
      float r = exp2f(mold - mnew);
      mrun[jj] = mnew;
      float rs = 0.f;
#pragma unroll
      for (int ni = 0; ni < 4; ni++) {
        float ppv = exp2f(sv[ni] - mnew);
        pw[jj][ni] = ppv;
        rs += ppv;
      }
      rs += __shfl_xor(rs, 1);
      rs += __shfl_xor(rs, 2);
      rs += __shfl_xor(rs, 4);
      rs += __shfl_xor(rs, 8);
      lrun[jj] = lrun[jj] * r + rs;
      rv[jj] = r;
    }
#pragma unroll
    for (int dti = 0; dti < 8; dti++) acc_o[dti] *= rv;

    // P -> LDS (bf16, swizzled), per-wave region
#pragma unroll
    for (int jj = 0; jj < 4; jj++)
#pragma unroll
      for (int ni = 0; ni < 4; ni++) {
        int qr = lg * 4 + jj;
        int key = ni * 16 + lr;
        *(bf16*)(pb + w * 2048 + qr * 128 + ((key * 2) ^ ((qr & 7) << 4))) = (bf16)pw[jj][ni];
      }

    // O += P V
    __builtin_amdgcn_s_setprio(1);
#pragma unroll
    for (int kc = 0; kc < 2; kc++) {
      int qr = lr;
      bf16x8 pf = *(const bf16x8*)(pb + w * 2048 + qr * 128 + (((kc * 4 + lg) ^ (qr & 7)) * 16));
#pragma unroll
      for (int dti = 0; dti < 8; dti++) {
        int d = dti * 16 + lr;
        bf16x8 vf = *(const bf16x8*)(vcur + d * 128 + (((kc * 4 + lg) ^ (d & 7)) * 16));
        acc_o[dti] = mfma16(pf, vf, acc_o[dti]);
      }
    }
    __builtin_amdgcn_s_setprio(0);

    __syncthreads();  // vmcnt(0)+lgkmcnt(0) drain + barrier: prefetch landed,
                      // everyone done reading cur -> safe to overwrite next iter
  }
  epilogue(q0);
}

extern "C" void kernel_launch(void* const* d_in, const int* in_sizes, int n_in,
                              void* d_out, int out_size, void* d_ws, size_t ws_size,
                              hipStream_t stream) {
  const float* x = (const float*)d_in[0];
  const float* rc = (const float*)d_in[1];
  const float* rs = (const float*)d_in[2];
  const float* wq = (const float*)d_in[3];
  const float* wk = (const float*)d_in[4];
  const float* wv = (const float*)d_in[5];
  const float* wo = (const float*)d_in[6];

  // Workspace layout with reuse (68 MB total):
  //   [0,        25165824)  qkv [4096][3072] bf16; dead after rope+vtrans ->
  //                         reused as ob [4096][2048] bf16
  //   [25165824, 41943040)  xb [4096][2048] bf16; dead after gemm1 ->
  //                         reused as q_r [2][16][2048][128] bf16
  //   [41943040, 54525952)  wqkvT [3072][2048] bf16
  //   [54525952, 62914560)  woT [2048][2048] bf16
  //   [62914560, 67108864)  k_r [2][4][2048][128] bf16
  //   [67108864, 71303168)  vT  [2][4][128][2048] bf16
  char* ws = (char*)d_ws;
  bf16* qkv = (bf16*)(ws + 0);
  bf16* ob = (bf16*)(ws + 0);
  bf16* xb = (bf16*)(ws + 25165824);
  bf16* q_r = (bf16*)(ws + 25165824);
  bf16* wqkvT = (bf16*)(ws + 41943040);
  bf16* woT = (bf16*)(ws + 54525952);
  bf16* k_r = (bf16*)(ws + 62914560);
  bf16* vTb = (bf16*)(ws + 67108864);
  float* out = (float*)d_out;

  cast_x_k<<<4096, 256, 0, stream>>>(x, xb);
  wtrans_k<<<dim3(32, 32), 256, 0, stream>>>(wq, 2048, wqkvT);
  wtrans_k<<<dim3(32, 8), 256, 0, stream>>>(wk, 512, wqkvT + (size_t)2048 * 2048);
  wtrans_k<<<dim3(32, 8), 256, 0, stream>>>(wv, 512, wqkvT + (size_t)2560 * 2048);
  wtrans_k<<<dim3(32, 32), 256, 0, stream>>>(wo, 2048, woT);
  gemm_bt<0><<<dim3(32, 24), 256, 0, stream>>>(xb, wqkvT, qkv, 4096, 3072, 2048);
  rope_k<<<4096, 256, 0, stream>>>(qkv, rc, rs, q_r, k_r);
  vtrans_k<<<dim3(32, 16), 256, 0, stream>>>(qkv, vTb);
  attn_k<<<dim3(16, 32), 256, 0, stream>>>(q_r, k_r, vTb, ob);
  gemm_bt<1><<<dim3(32, 16), 256, 0, stream>>>(ob, woT, out, 4096, 2048, 2048);
}

// Round 5
// 322.628 us; speedup vs baseline: 1.1468x; 1.0083x over previous
//
#include <hip/hip_runtime.h>
#include <cstdint>
#include <cstddef>

typedef __bf16 bf16;
typedef unsigned short u16;
typedef __bf16 bf16x8 __attribute__((ext_vector_type(8)));
typedef float f32x4 __attribute__((ext_vector_type(4)));

#define NB 2
#define NT 2048
#define NC 2048
#define NH 16
#define NKV 4
#define ND 128

// scale * log2(e) = (1/sqrt(128)) * 1.4426950408889634
#define SLOG2E 0.12751744061898285f

static __device__ __forceinline__ void gload16(const void* g, void* l) {
  __builtin_amdgcn_global_load_lds(
      (const __attribute__((address_space(1))) unsigned int*)g,
      (__attribute__((address_space(3))) unsigned int*)l, 16, 0, 0);
}

static __device__ __forceinline__ f32x4 mfma16(bf16x8 a, bf16x8 b, f32x4 c) {
  return __builtin_amdgcn_mfma_f32_16x16x32_bf16(a, b, c, 0, 0, 0);
}

// ---------------- cast x (f32 -> bf16), 8 elems/thread ----------------
__global__ void cast_x_k(const float* __restrict__ x, bf16* __restrict__ xb) {
  size_t i = ((size_t)blockIdx.x * 256 + threadIdx.x) * 8;
  float4 v0 = *(const float4*)(x + i);
  float4 v1 = *(const float4*)(x + i + 4);
  bf16x8 o;
  o[0] = (bf16)v0.x; o[1] = (bf16)v0.y; o[2] = (bf16)v0.z; o[3] = (bf16)v0.w;
  o[4] = (bf16)v1.x; o[5] = (bf16)v1.y; o[6] = (bf16)v1.z; o[7] = (bf16)v1.w;
  *(bf16x8*)(xb + i) = o;
}

// ------------- weight transpose+cast: dst[n][k] = src[k][n] -------------
__global__ void wtrans_k(const float* __restrict__ src, int N, bf16* __restrict__ dst) {
  __shared__ float tile[64][65];
  int k0 = blockIdx.x * 64, n0 = blockIdx.y * 64;
  int tid = threadIdx.x, c = tid & 63, r4 = tid >> 6;
#pragma unroll 4
  for (int i = 0; i < 16; i++) {
    int rr = i * 4 + r4;
    tile[c][rr] = src[(size_t)(k0 + rr) * N + n0 + c];
  }
  __syncthreads();
#pragma unroll 4
  for (int i = 0; i < 16; i++) {
    int nn = i * 4 + r4;
    dst[(size_t)(n0 + nn) * 2048 + k0 + c] = (bf16)tile[nn][c];
  }
}

// ---------------- GEMM: C[M][N] = A[M][K] * Bt[N][K]^T ----------------
// 128x128 tile, BK=64, 4 waves. 1D grid with bijective XCD-chunk remap
// (nwg % 8 == 0) so consecutive swz ids share an XCD L2.
template <int F32OUT>
__global__ __launch_bounds__(256, 2) void gemm_bt(const bf16* __restrict__ A,
                                                  const bf16* __restrict__ Bt,
                                                  void* __restrict__ Cp,
                                                  int M, int N, int K, int nbx) {
  __shared__ __align__(16) char aT[16384];
  __shared__ __align__(16) char bT[16384];
  const int nwg = gridDim.x;
  const int q8 = nwg >> 3;
  const int swz = (blockIdx.x & 7) * q8 + (blockIdx.x >> 3);
  const int m0 = (swz % nbx) * 128, n0 = (swz / nbx) * 128;
  const int tid = threadIdx.x, w = tid >> 6, l = tid & 63;
  const int lr = l & 15, lg = l >> 4;
  const int wm = (w >> 1) * 64, wn = (w & 1) * 64;
  f32x4 acc[4][4] = {};
  for (int k0 = 0; k0 < K; k0 += 64) {
#pragma unroll
    for (int i = 0; i < 4; i++) {
      int p = i * 256 + tid;
      int row = p >> 3, sl = (p & 7) ^ (row & 7);
      gload16(A + (size_t)(m0 + row) * K + (k0 + sl * 8), aT + (i * 256 + w * 64) * 16);
      gload16(Bt + (size_t)(n0 + row) * K + (k0 + sl * 8), bT + (i * 256 + w * 64) * 16);
    }
    __syncthreads();
#pragma unroll
    for (int kc = 0; kc < 2; kc++) {
      bf16x8 af[4], bfr[4];
#pragma unroll
      for (int mi = 0; mi < 4; mi++) {
        int row = wm + mi * 16 + lr;
        af[mi] = *(const bf16x8*)(aT + row * 128 + (((kc * 4 + lg) ^ (row & 7)) * 16));
      }
#pragma unroll
      for (int ni = 0; ni < 4; ni++) {
        int row = wn + ni * 16 + lr;
        bfr[ni] = *(const bf16x8*)(bT + row * 128 + (((kc * 4 + lg) ^ (row & 7)) * 16));
      }
#pragma unroll
      for (int mi = 0; mi < 4; mi++)
#pragma unroll
        for (int ni = 0; ni < 4; ni++)
          acc[mi][ni] = mfma16(af[mi], bfr[ni], acc[mi][ni]);
    }
    __syncthreads();
  }
#pragma unroll
  for (int mi = 0; mi < 4; mi++)
#pragma unroll
    for (int ni = 0; ni < 4; ni++)
#pragma unroll
      for (int j = 0; j < 4; j++) {
        size_t row = (size_t)m0 + wm + mi * 16 + lg * 4 + j;
        size_t col = (size_t)n0 + wn + ni * 16 + lr;
        if (F32OUT)
          ((float*)Cp)[row * N + col] = acc[mi][ni][j];
        else
          ((bf16*)Cp)[row * N + col] = (bf16)acc[mi][ni][j];
      }
}

// ---------------- RoPE on q and k (f32 math), relayout ----------------
__global__ void rope_k(const bf16* __restrict__ qkv, const float* __restrict__ cosg,
                       const float* __restrict__ sing, bf16* __restrict__ q_r,
                       bf16* __restrict__ k_r) {
  int blk = blockIdx.x;
  int b = blk >> 11, t = blk & 2047;
  const bf16* row = qkv + (size_t)blk * 3072;
  int tid = threadIdx.x;
#pragma unroll
  for (int i = 0; i < 4; i++) {
    int idx = i * 256 + tid;
    int hh = idx >> 6, dp = idx & 63;
    float a = (float)row[hh * 128 + dp], b2 = (float)row[hh * 128 + dp + 64];
    float c = cosg[t * 128 + dp], sn = sing[t * 128 + dp];
    bf16* dst = q_r + ((size_t)(b * NH + hh) * NT + t) * ND + dp;
    dst[0] = (bf16)(a * c - b2 * sn);
    dst[64] = (bf16)(b2 * c + a * sn);
  }
  {
    int kvh = tid >> 6, dp = tid & 63;
    float a = (float)row[2048 + kvh * 128 + dp], b2 = (float)row[2048 + kvh * 128 + dp + 64];
    float c = cosg[t * 128 + dp], sn = sing[t * 128 + dp];
    bf16* dst = k_r + ((size_t)(b * NKV + kvh) * NT + t) * ND + dp;
    dst[0] = (bf16)(a * c - b2 * sn);
    dst[64] = (bf16)(b2 * c + a * sn);
  }
}

// --------- v transpose: qkv v-cols -> vT[b][kv][d][t] (LDS tiled) ---------
__global__ void vtrans_k(const bf16* __restrict__ qkv, bf16* __restrict__ vT) {
  __shared__ u16 tile[64][66];
  int y = blockIdx.y;
  int b = y >> 3, kvh = (y >> 1) & 3, dh = y & 1;
  int t0 = blockIdx.x * 64;
  int tid = threadIdx.x, c = tid & 63, r4 = tid >> 6;
#pragma unroll 4
  for (int i = 0; i < 16; i++) {
    int rr = i * 4 + r4;  // t index
    tile[c][rr] = *(const u16*)(qkv + (size_t)(b * NT + t0 + rr) * 3072 + 2560 + kvh * 128 + dh * 64 + c);
  }
  __syncthreads();
#pragma unroll 4
  for (int i = 0; i < 16; i++) {
    int dd = i * 4 + r4;
    *(u16*)(vT + ((size_t)(b * NKV + kvh) * ND + dh * 64 + dd) * NT + t0 + c) = tile[dd][c];
  }
}

// ---------------- flash attention (causal, GQA 4:1) ----------------
// 1D grid 512 with XCD-chunk remap -> p = swz&15, bh = swz>>4 (16 blocks of
// one (b,h) cluster on one XCD). Balanced q-tile pair (p, 31-p): 33 KV tiles.
// K/V double-buffered; prefetch-before-compute; one barrier per tile.
// Causal mask applied only on each q-tile's diagonal KV tile.
__global__ __launch_bounds__(256, 2) void attn_k(const bf16* __restrict__ q_r,
                                                 const bf16* __restrict__ k_r,
                                                 const bf16* __restrict__ vT,
                                                 bf16* __restrict__ o) {
  __shared__ __align__(16) char kb[2][16384];  // [64 key][128 d] swz
  __shared__ __align__(16) char vb[2][16384];  // [128 d][64 key] swz
  __shared__ __align__(16) char pb[8192];      // per-wave [16 q][64 key] swz
  const int swzid = (blockIdx.x & 7) * 64 + (blockIdx.x >> 3);
  const int p = swzid & 15, bh = swzid >> 4;
  const int b = bh >> 4, h = bh & 15, kvh = h >> 2;
  const int tid = threadIdx.x, w = tid >> 6, l = tid & 63;
  const int lr = l & 15, lg = l >> 4;
  const int nta = p + 1;       // KV tiles for q-tile A
  const int ntot = 33;         // + (32 - p) for q-tile B
  const int qA = p * 64, qB = (31 - p) * 64;

  const bf16* kg = k_r + (size_t)(b * NKV + kvh) * NT * ND;
  const bf16* vg = vT + (size_t)(b * NKV + kvh) * ND * NT;
  const bf16* qbase = q_r + (size_t)(b * NH + h) * NT * ND;

  bf16x8 qf[4];
  f32x4 acc_o[8];
  float mrun[4], lrun[4];

  auto loadq = [&](int qrow0) {
#pragma unroll
    for (int kc = 0; kc < 4; kc++)
      qf[kc] = *(const bf16x8*)(qbase + (size_t)(qrow0 + w * 16 + lr) * ND + kc * 32 + lg * 8);
  };
  auto reset_state = [&]() {
#pragma unroll
    for (int dti = 0; dti < 8; dti++) acc_o[dti] = f32x4{0.f, 0.f, 0.f, 0.f};
#pragma unroll
    for (int jj = 0; jj < 4; jj++) { mrun[jj] = -1e30f; lrun[jj] = 0.f; }
  };
  auto epilogue = [&](int qrow0) {
    f32x4 inv;
#pragma unroll
    for (int jj = 0; jj < 4; jj++) inv[jj] = 1.0f / lrun[jj];
#pragma unroll
    for (int dti = 0; dti < 8; dti++) {
      f32x4 ov = acc_o[dti] * inv;
#pragma unroll
      for (int jj = 0; jj < 4; jj++) {
        size_t orow = (size_t)b * NT + qrow0 + w * 16 + lg * 4 + jj;
        o[orow * NC + h * ND + dti * 16 + lr] = (bf16)ov[jj];
      }
    }
  };
  auto stage = [&](char* kd, char* vd, int kv0s) {
#pragma unroll
    for (int i = 0; i < 4; i++) {
      int pp = i * 256 + tid;
      int krow = pp >> 4, ksl = (pp & 15) ^ (krow & 7);
      gload16(kg + (size_t)(kv0s + krow) * ND + ksl * 8, kd + (i * 256 + w * 64) * 16);
      int vrow = pp >> 3, vsl = (pp & 7) ^ (vrow & 7);
      gload16(vg + (size_t)vrow * NT + kv0s + vsl * 8, vd + (i * 256 + w * 64) * 16);
    }
  };

  loadq(qA);
  reset_state();
  int q0 = qA;

  stage(kb[0], vb[0], 0);
  __syncthreads();

  for (int tt = 0; tt < ntot; ++tt) {
    const int cur = tt & 1;
    char* kcur = kb[cur];
    char* vcur = vb[cur];
    if (tt + 1 < ntot) {
      int nx = tt + 1;
      int kv0n = (nx < nta ? nx : nx - nta) * 64;
      stage(kb[cur ^ 1], vb[cur ^ 1], kv0n);
    }
    if (tt == nta) {
      epilogue(qA);
      loadq(qB);
      reset_state();
      q0 = qB;
    }
    const int kv0 = (tt < nta ? tt : tt - nta) * 64;
    const bool diag = (tt == nta - 1) || (tt == ntot - 1);

    // S = Q K^T
    f32x4 sacc[4] = {};
    __builtin_amdgcn_s_setprio(1);
#pragma unroll
    for (int kc = 0; kc < 4; kc++) {
#pragma unroll
      for (int ni = 0; ni < 4; ni++) {
        int key = ni * 16 + lr;
        bf16x8 kf = *(const bf16x8*)(kcur + key * 256 + (((kc * 4 + lg) ^ (key & 7)) * 16));
        sacc[ni] = mfma16(qf[kc], kf, sacc[ni]);
      }
    }
    __builtin_amdgcn_s_setprio(0);

    // online softmax (exp2 domain), 16-lane row reduce.
    // Causal mask needed only on the diagonal tile (proof: for non-diag
    // tiles, max key = kv0+63 <= q0-1 < qrow for all rows in the q-tile).
    float pw[4][4];
    f32x4 rv;
#pragma unroll
    for (int jj = 0; jj < 4; jj++) {
      int qrow = q0 + w * 16 + lg * 4 + jj;
      float sv[4];
      float mt = -1e30f;
#pragma unroll
      for (int ni = 0; ni < 4; ni++) {
        float xv = sacc[ni][jj] * SLOG2E;
        if (diag) {
          int key = kv0 + ni * 16 + lr;
          xv = (key <= qrow) ? xv : -1e30f;
        }
        sv[ni] = xv;
        mt = fmaxf(mt, xv);
      }
      mt = fmaxf(mt, __shfl_xor(mt, 1));
      mt = fmaxf(mt, __shfl_xor(mt, 2));
      mt = fmaxf(mt, __shfl_xor(mt, 4));
      mt = fmaxf(mt, __shfl_xor(mt, 8));
      float mold = mrun[jj];
      float mnew = fmaxf(mold, mt);
      float r = exp2f(mold - mnew);
      mrun[jj] = mnew;
      float rs = 0.f;
#pragma unroll
      for (int ni = 0; ni < 4; ni++) {
        float ppv = exp2f(sv[ni] - mnew);
        pw[jj][ni] = ppv;
        rs += ppv;
      }
      rs += __shfl_xor(rs, 1);
      rs += __shfl_xor(rs, 2);
      rs += __shfl_xor(rs, 4);
      rs += __shfl_xor(rs, 8);
      lrun[jj] = lrun[jj] * r + rs;
      rv[jj] = r;
    }
#pragma unroll
    for (int dti = 0; dti < 8; dti++) acc_o[dti] *= rv;

    // P -> LDS (bf16, swizzled), per-wave region
#pragma unroll
    for (int jj = 0; jj < 4; jj++)
#pragma unroll
      for (int ni = 0; ni < 4; ni++) {
        int qr = lg * 4 + jj;
        int key = ni * 16 + lr;
        *(bf16*)(pb + w * 2048 + qr * 128 + ((key * 2) ^ ((qr & 7) << 4))) = (bf16)pw[jj][ni];
      }

    // O += P V
    __builtin_amdgcn_s_setprio(1);
#pragma unroll
    for (int kc = 0; kc < 2; kc++) {
      int qr = lr;
      bf16x8 pf = *(const bf16x8*)(pb + w * 2048 + qr * 128 + (((kc * 4 + lg) ^ (qr & 7)) * 16));
#pragma unroll
      for (int dti = 0; dti < 8; dti++) {
        int d = dti * 16 + lr;
        bf16x8 vf = *(const bf16x8*)(vcur + d * 128 + (((kc * 4 + lg) ^ (d & 7)) * 16));
        acc_o[dti] = mfma16(pf, vf, acc_o[dti]);
      }
    }
    __builtin_amdgcn_s_setprio(0);

    __syncthreads();  // drain prefetch + all waves done reading cur buffers
  }
  epilogue(q0);
}

extern "C" void kernel_launch(void* const* d_in, const int* in_sizes, int n_in,
                              void* d_out, int out_size, void* d_ws, size_t ws_size,
                              hipStream_t stream) {
  const float* x = (const float*)d_in[0];
  const float* rc = (const float*)d_in[1];
  const float* rs = (const float*)d_in[2];
  const float* wq = (const float*)d_in[3];
  const float* wk = (const float*)d_in[4];
  const float* wv = (const float*)d_in[5];
  const float* wo = (const float*)d_in[6];

  // Workspace layout with reuse (68 MB total):
  //   [0,        25165824)  qkv [4096][3072] bf16; dead after rope+vtrans ->
  //                         reused as ob [4096][2048] bf16
  //   [25165824, 41943040)  xb [4096][2048] bf16; dead after gemm1 ->
  //                         reused as q_r [2][16][2048][128] bf16
  //   [41943040, 54525952)  wqkvT [3072][2048] bf16
  //   [54525952, 62914560)  woT [2048][2048] bf16
  //   [62914560, 67108864)  k_r [2][4][2048][128] bf16
  //   [67108864, 71303168)  vT  [2][4][128][2048] bf16
  char* ws = (char*)d_ws;
  bf16* qkv = (bf16*)(ws + 0);
  bf16* ob = (bf16*)(ws + 0);
  bf16* xb = (bf16*)(ws + 25165824);
  bf16* q_r = (bf16*)(ws + 25165824);
  bf16* wqkvT = (bf16*)(ws + 41943040);
  bf16* woT = (bf16*)(ws + 54525952);
  bf16* k_r = (bf16*)(ws + 62914560);
  bf16* vTb = (bf16*)(ws + 67108864);
  float* out = (float*)d_out;

  cast_x_k<<<4096, 256, 0, stream>>>(x, xb);
  wtrans_k<<<dim3(32, 32), 256, 0, stream>>>(wq, 2048, wqkvT);
  wtrans_k<<<dim3(32, 8), 256, 0, stream>>>(wk, 512, wqkvT + (size_t)2048 * 2048);
  wtrans_k<<<dim3(32, 8), 256, 0, stream>>>(wv, 512, wqkvT + (size_t)2560 * 2048);
  wtrans_k<<<dim3(32, 32), 256, 0, stream>>>(wo, 2048, woT);
  gemm_bt<0><<<768, 256, 0, stream>>>(xb, wqkvT, qkv, 4096, 3072, 2048, 32);
  rope_k<<<4096, 256, 0, stream>>>(qkv, rc, rs, q_r, k_r);
  vtrans_k<<<dim3(32, 16), 256, 0, stream>>>(qkv, vTb);
  attn_k<<<512, 256, 0, stream>>>(q_r, k_r, vTb, ob);
  gemm_bt<1><<<512, 256, 0, stream>>>(ob, woT, out, 4096, 2048, 2048, 32);
}